// Round 15
// baseline (67.629 us; speedup 1.0000x reference)
//
#include <hip/hip_runtime.h>

// RetinaNetFocalLoss on MI355X (gfx950).
// Inputs: clas_preds (16,49152,80) f32, bbox_preds (16,49152,4) f32,
//         bbox_tgts (16,64,4) f32 tlbr, clas_tgts (16,64) i32, anchors (49152,4) f32 cthw.
// Output: single f32 scalar.
//
// v15 = v14 (fused prefetch-first blocks, 57.2 µs) + issue-op cuts, retested
// post-fusion (regime flipped to VALU-issue-bound per R8's 52 µs VALUBusy):
//   - focal4q regular VALU packed to f32x2 (v_pk_*), trans unchanged (9/float4)
//   - match: pk intersection + 2-track argmax (even/odd targets, merged once)
//   - hot-class focal correction applied IN the stream from register data
//     (removes scattered clas_preds load + trans from the match phase)

#define A_CNT 49152
#define T_CNT 64
#define C_CNT 80
#define ABLK  256
#define NBLK  (A_CNT / ABLK)   // 192
#define B_CNT 16
#define NSLOT (B_CNT * NBLK)   // 3072

#define LN2   0.6931471806f
#define RLN2  1.44269504f

typedef float f32x4 __attribute__((ext_vector_type(4)));
typedef float f32x2 __attribute__((ext_vector_type(2)));

// sum_i sigma(x_i)^2 * log2(1+e^{x_i}) over a float4.
// 4 exp + 1 rcp + 4 log (trans) + ~13 packed regular issue slots.
__device__ __forceinline__ float focal4q(f32x4 v) {
    float e0 = __builtin_amdgcn_exp2f(v.x * RLN2);
    float e1 = __builtin_amdgcn_exp2f(v.y * RLN2);
    float e2 = __builtin_amdgcn_exp2f(v.z * RLN2);
    float e3 = __builtin_amdgcn_exp2f(v.w * RLN2);
    f32x2 eA = {e0, e1}, eB = {e2, e3};
    f32x2 tA = eA + 1.0f, tB = eB + 1.0f;            // pk_add
    float t01 = tA.x * tA.y, t23 = tB.x * tB.y;
    float r   = __builtin_amdgcn_rcpf(t01 * t23);    // 1/(t0 t1 t2 t3)
    float p   = r * t23, q = r * t01;                // 1/(t0 t1), 1/(t2 t3)
    f32x2 invA = (f32x2){p, p} * (f32x2){tA.y, tA.x};   // {1/t0, 1/t1}
    f32x2 invB = (f32x2){q, q} * (f32x2){tB.y, tB.x};   // {1/t2, 1/t3}
    f32x2 sA = eA * invA, sB = eB * invB;            // sigmoids
    f32x2 LA = { __builtin_amdgcn_logf(tA.x), __builtin_amdgcn_logf(tA.y) };
    f32x2 LB = { __builtin_amdgcn_logf(tB.x), __builtin_amdgcn_logf(tB.y) };
    f32x2 a2 = (sA * sA) * LA + (sB * sB) * LB;      // pk_mul + pk_fma
    return a2.x + a2.y;
}

// hot-class correction in true units; d = class offset within the float4.
__device__ __forceinline__ float hotfix(f32x4 cur, unsigned d) {
    float x = (d == 0) ? cur.x : (d == 1) ? cur.y : (d == 2) ? cur.z : cur.w;
    float e  = __builtin_amdgcn_exp2f(x * RLN2);
    float t  = 1.0f + e;
    float inv = __builtin_amdgcn_rcpf(t);
    float ps = e * inv, qq = 1.0f - ps;
    float sp = LN2 * __builtin_amdgcn_logf(t);       // softplus(x)
    return 0.75f * qq * qq * (sp - x) - 0.25f * ps * ps * sp;
}

__global__ __launch_bounds__(ABLK) void rnfl_main(
    const float* __restrict__ clas_preds,
    const float* __restrict__ bbox_preds,
    const float* __restrict__ bbox_tgts,
    const int*   __restrict__ clas_tgts,
    const float* __restrict__ anchors,
    float* __restrict__ bb_part,
    float* __restrict__ fl_part,
    float* __restrict__ m_part)
{
    const int tid  = threadIdx.x;
    const int g    = blockIdx.x;                // [0, 3072)
    const int lane = tid & 63, wave = tid >> 6;
    const int b    = g / NBLK;
    const int bx   = g - b * NBLK;
    const int a0   = bx * ABLK;

    __shared__ float4 tbox[T_CNT];
    __shared__ f32x2  tX1v[T_CNT / 2], tY1v[T_CNT / 2];
    __shared__ f32x2  tX2v[T_CNT / 2], tY2v[T_CNT / 2];
    __shared__ f32x2  tSv[T_CNT / 2];
    __shared__ int    tcl[T_CNT];
    __shared__ int    codes[ABLK];
    __shared__ float  rv[4][4];

    const f32x4* cp4 = reinterpret_cast<const f32x4*>(clas_preds)
                     + ((size_t)b * A_CNT + a0) * (C_CNT / 4);

    // ---- 1. issue the focal prefetches FIRST (8 in flight during match) ----
    f32x4 buf[8];
#pragma unroll
    for (int i = 0; i < 8; ++i)
        buf[i] = cp4[i * ABLK + tid];

    // ---- 2. stage targets into LDS ----
    if (tid < T_CNT) {
        float4 bt = reinterpret_cast<const float4*>(bbox_tgts)[b * T_CNT + tid];
        // tlbr -> cthw -> tlbr (reference roundtrip)
        float cx = (bt.x + bt.z) * 0.5f;
        float cy = (bt.y + bt.w) * 0.5f;
        float sx = bt.z - bt.x;
        float sy = bt.w - bt.y;
        float4 tb;
        tb.x = cx - sx * 0.5f;
        tb.y = cy - sy * 0.5f;
        tb.z = cx + sx * 0.5f;
        tb.w = cy + sy * 0.5f;
        tbox[tid] = tb;
        ((float*)tX1v)[tid] = tb.x;
        ((float*)tY1v)[tid] = tb.y;
        ((float*)tX2v)[tid] = tb.z;
        ((float*)tY2v)[tid] = tb.w;
        ((float*)tSv)[tid]  = sx * sy + 1e-8f;
        tcl[tid] = clas_tgts[b * T_CNT + tid];
    }
    __syncthreads();

    // ---- 3. match: pk intersection + 2-track argmax (loads fly underneath) ----
    const int a = a0 + tid;
    float4 anc = reinterpret_cast<const float4*>(anchors)[a];
    const float ax1 = anc.x - anc.z * 0.5f;
    const float ay1 = anc.y - anc.w * 0.5f;
    const float ax2 = anc.x + anc.z * 0.5f;
    const float ay2 = anc.y + anc.w * 0.5f;
    const float areaA = anc.z * anc.w;
    const f32x2 A1 = {ax1, ax1}, B1 = {ay1, ay1};
    const f32x2 A2 = {ax2, ax2}, B2 = {ay2, ay2};
    const f32x2 SA = {areaA, areaA};
    const f32x2 Z  = {0.0f, 0.0f};

    float bnX = -1.0f, bdX = 1.0f;   // track even targets
    float bnY = -1.0f, bdY = 1.0f;   // track odd targets
    int   bjx = 0, bjy = 1;
#pragma unroll 4
    for (int p = 0; p < T_CNT / 2; ++p) {
        f32x2 ix1 = __builtin_elementwise_max(A1, tX1v[p]);
        f32x2 iy1 = __builtin_elementwise_max(B1, tY1v[p]);
        f32x2 ix2 = __builtin_elementwise_min(A2, tX2v[p]);
        f32x2 iy2 = __builtin_elementwise_min(B2, tY2v[p]);
        f32x2 w = __builtin_elementwise_max(ix2 - ix1, Z);
        f32x2 h = __builtin_elementwise_max(iy2 - iy1, Z);
        f32x2 interV = w * h;
        f32x2 denV = (SA + tSv[p]) - interV;
        // independent chains (ILP x2); each keeps first-max within its track
        if (interV.x * bdX > bnX * denV.x) { bnX = interV.x; bdX = denV.x; bjx = 2 * p; }
        if (interV.y * bdY > bnY * denV.y) { bnY = interV.y; bdY = denV.y; bjy = 2 * p + 1; }
    }
    // merge: first-max overall (tie -> lower index)
    float vx = bnX * bdY, vy = bnY * bdX;
    float bn, bd; int bj;
    if (vx > vy || (vx == vy && bjx < bjy)) { bn = bnX; bd = bdX; bj = bjx; }
    else                                    { bn = bnY; bd = bdY; bj = bjy; }

    int   code;
    float bb   = 0.0f;
    float mloc = 0.0f;

    if (bn > 0.5f * bd) {                    // iou > MATCH_THR
        mloc = 1.0f;
        code = tcl[bj] - 1;                  // hot class in [0,79]
        float4 tb = tbox[bj];
        float gx = (tb.x + tb.z) * 0.5f;
        float gy = (tb.y + tb.w) * 0.5f;
        float gw = tb.z - tb.x;
        float gh = tb.w - tb.y;
        float4 bp = reinterpret_cast<const float4*>(bbox_preds)[(size_t)b * A_CNT + a];
        float t0 = ((gx - anc.x) / anc.z) * 10.0f;       // / SCALE 0.1
        float t1 = ((gy - anc.y) / anc.w) * 10.0f;
        float t2 = __logf(gw / anc.z + 1e-8f) * 5.0f;    // / SCALE 0.2
        float t3 = __logf(gh / anc.w + 1e-8f) * 5.0f;
        float d, ad;
        d = bp.x - t0; ad = fabsf(d); bb += (ad < 1.0f) ? 0.5f * d * d : ad - 0.5f;
        d = bp.y - t1; ad = fabsf(d); bb += (ad < 1.0f) ? 0.5f * d * d : ad - 0.5f;
        d = bp.z - t2; ad = fabsf(d); bb += (ad < 1.0f) ? 0.5f * d * d : ad - 0.5f;
        d = bp.w - t3; ad = fabsf(d); bb += (ad < 1.0f) ? 0.5f * d * d : ad - 0.5f;
    } else {
        code = (bn >= 0.4f * bd) ? -2 : -1;  // -2 excluded, -1 background
    }
    codes[tid] = code;
    __syncthreads();

    // ---- 4. masked focal stream; hot correction from register data ----
    float acc = 0.0f;   // masked raw focal_l2 sum
    float hot = 0.0f;   // true-unit hot corrections
#pragma unroll
    for (int k = 0; k < 12; ++k) {
        f32x4 cur = buf[k & 7];
        buf[k & 7] = cp4[(k + 8) * ABLK + tid];
        int f  = k * ABLK + tid;
        int al = (unsigned)f / 20u;
        int cc = codes[al];
        float m = (cc >= -1) ? 1.0f : 0.0f;
        acc = fmaf(m, focal4q(cur), acc);
        unsigned d = (unsigned)(cc - (f - al * 20) * 4);
        if (d < 4u) hot += hotfix(cur, d);
    }
#pragma unroll
    for (int k = 12; k < 20; ++k) {
        f32x4 cur = buf[k & 7];
        int f  = k * ABLK + tid;
        int al = (unsigned)f / 20u;
        int cc = codes[al];
        float m = (cc >= -1) ? 1.0f : 0.0f;
        acc = fmaf(m, focal4q(cur), acc);
        unsigned d = (unsigned)(cc - (f - al * 20) * 4);
        if (d < 4u) hot += hotfix(cur, d);
    }
    float fl = fmaf(acc, 0.25f * LN2, hot);

    // ---- 5. block reduction of {bb, fl, m} ----
#pragma unroll
    for (int off = 32; off > 0; off >>= 1) {
        bb   += __shfl_down(bb, off);
        fl   += __shfl_down(fl, off);
        mloc += __shfl_down(mloc, off);
    }
    if (lane == 0) { rv[wave][0] = bb; rv[wave][1] = fl; rv[wave][2] = mloc; }
    __syncthreads();
    if (tid == 0) {
        int slot = b * NBLK + bx;
        bb_part[slot] = rv[0][0] + rv[1][0] + rv[2][0] + rv[3][0];
        fl_part[slot] = rv[0][1] + rv[1][1] + rv[2][1] + rv[3][1];
        m_part[slot]  = rv[0][2] + rv[1][2] + rv[2][2] + rv[3][2];
    }
}

// ---------- Finalize (separate dispatch; coalesced -> LDS -> reduce) ----------
__global__ __launch_bounds__(256) void rnfl_final(
    const float* __restrict__ bb_part,
    const float* __restrict__ fl_part,
    const float* __restrict__ m_part,
    float* __restrict__ out)
{
    __shared__ float bbL[NSLOT], flL[NSLOT], mL[NSLOT];  // 36 KB
    __shared__ float wacc[4];
    const int tid = threadIdx.x, lane = tid & 63, wave = tid >> 6;

#pragma unroll
    for (int k = 0; k < NSLOT / 256; ++k) {   // 12 coalesced loads per array
        int s = k * 256 + tid;
        bbL[s] = bb_part[s];
        flL[s] = fl_part[s];
        mL[s]  = m_part[s];
    }
    __syncthreads();

    float lacc = 0.0f;
    for (int img = wave; img < B_CNT; img += 4) {
        float bb = 0.0f, fl = 0.0f, m = 0.0f;
#pragma unroll
        for (int s = 0; s < 3; ++s) {         // 3*64 = 192 = NBLK
            int i = img * NBLK + s * 64 + lane;
            bb += bbL[i];
            fl += flL[i];
            m  += mL[i];
        }
#pragma unroll
        for (int off = 32; off > 0; off >>= 1) {
            bb += __shfl_down(bb, off);
            fl += __shfl_down(fl, off);
            m  += __shfl_down(m, off);
        }
        if (lane == 0)
            lacc += bb / fmaxf(m * 4.0f, 1.0f) + fl / fmaxf(m, 1.0f);
    }
    if (lane == 0) wacc[wave] = lacc;
    __syncthreads();
    if (tid == 0)
        out[0] = (wacc[0] + wacc[1] + wacc[2] + wacc[3]) / (float)B_CNT;
}

extern "C" void kernel_launch(void* const* d_in, const int* in_sizes, int n_in,
                              void* d_out, int out_size, void* d_ws, size_t ws_size,
                              hipStream_t stream)
{
    const float* clas_preds = (const float*)d_in[0];
    const float* bbox_preds = (const float*)d_in[1];
    const float* bbox_tgts  = (const float*)d_in[2];
    const int*   clas_tgts  = (const int*)d_in[3];
    const float* anchors    = (const float*)d_in[4];
    float* out = (float*)d_out;

    float* bb_part = (float*)d_ws;
    float* fl_part = bb_part + NSLOT;
    float* m_part  = fl_part + NSLOT;

    rnfl_main<<<NSLOT, ABLK, 0, stream>>>(clas_preds, bbox_preds, bbox_tgts,
                                          clas_tgts, anchors,
                                          bb_part, fl_part, m_part);
    rnfl_final<<<1, 256, 0, stream>>>(bb_part, fl_part, m_part, out);
}

// Round 16
// 60.861 us; speedup vs baseline: 1.1112x; 1.1112x over previous
//
#include <hip/hip_runtime.h>

// RetinaNetFocalLoss on MI355X (gfx950).
// Inputs: clas_preds (16,49152,80) f32, bbox_preds (16,49152,4) f32,
//         bbox_tgts (16,64,4) f32 tlbr, clas_tgts (16,64) i32, anchors (49152,4) f32 cthw.
// Output: single f32 scalar.
//
// v16 = v14 (fused prefetch-first, 57.2 µs — best) + ONE change: focal4q's
// regular VALU packed to f32x2 (v_pk_* with op_sel swizzles). R15's other
// two changes (hot-in-stream, 2-track argmax) are REVERTED — the per-k
// LDS+branch they added to the stream loop cost +10 µs (issue-sensitive).

#define A_CNT 49152
#define T_CNT 64
#define C_CNT 80
#define ABLK  256
#define NBLK  (A_CNT / ABLK)   // 192
#define B_CNT 16
#define NSLOT (B_CNT * NBLK)   // 3072

#define LN2   0.6931471806f
#define RLN2  1.44269504f

typedef float f32x4 __attribute__((ext_vector_type(4)));
typedef float f32x2 __attribute__((ext_vector_type(2)));

// sum_i sigma(x_i)^2 * log2(1+e^{x_i}) over a float4 (quad-rcp).
// Trans: 4 exp + 1 rcp + 4 log. Regular VALU packed to f32x2.
__device__ __forceinline__ float focal4q(f32x4 v) {
    f32x2 xsA = (f32x2){v.x, v.y} * RLN2;            // pk_mul
    f32x2 xsB = (f32x2){v.z, v.w} * RLN2;
    f32x2 eA = { __builtin_amdgcn_exp2f(xsA.x), __builtin_amdgcn_exp2f(xsA.y) };
    f32x2 eB = { __builtin_amdgcn_exp2f(xsB.x), __builtin_amdgcn_exp2f(xsB.y) };
    f32x2 tA = eA + 1.0f, tB = eB + 1.0f;            // pk_add
    float t01 = tA.x * tA.y, t23 = tB.x * tB.y;
    float r   = __builtin_amdgcn_rcpf(t01 * t23);    // 1/(t0 t1 t2 t3)
    float p   = r * t23, q = r * t01;                // 1/(t0 t1), 1/(t2 t3)
    f32x2 invA = (f32x2){p, p} * (f32x2){tA.y, tA.x};   // {1/t0, 1/t1} (op_sel)
    f32x2 invB = (f32x2){q, q} * (f32x2){tB.y, tB.x};   // {1/t2, 1/t3}
    f32x2 sA = eA * invA, sB = eB * invB;            // sigmoids
    f32x2 LA = { __builtin_amdgcn_logf(tA.x), __builtin_amdgcn_logf(tA.y) };
    f32x2 LB = { __builtin_amdgcn_logf(tB.x), __builtin_amdgcn_logf(tB.y) };
    f32x2 a2 = (sA * sA) * LA + (sB * sB) * LB;      // pk_mul + pk_fma
    return a2.x + a2.y;
}

__global__ __launch_bounds__(ABLK) void rnfl_main(
    const float* __restrict__ clas_preds,
    const float* __restrict__ bbox_preds,
    const float* __restrict__ bbox_tgts,
    const int*   __restrict__ clas_tgts,
    const float* __restrict__ anchors,
    float* __restrict__ bb_part,
    float* __restrict__ fl_part,
    float* __restrict__ m_part)
{
    const int tid  = threadIdx.x;
    const int g    = blockIdx.x;                // [0, 3072)
    const int lane = tid & 63, wave = tid >> 6;
    const int b    = g / NBLK;
    const int bx   = g - b * NBLK;
    const int a0   = bx * ABLK;

    __shared__ float4 tbox[T_CNT];
    __shared__ float  taT[T_CNT];
    __shared__ int    tcl[T_CNT];
    __shared__ int    codes[ABLK];
    __shared__ float  rv[4][4];

    const f32x4* cp4 = reinterpret_cast<const f32x4*>(clas_preds)
                     + ((size_t)b * A_CNT + a0) * (C_CNT / 4);

    // ---- 1. issue the focal prefetches FIRST (8 in flight during match) ----
    f32x4 buf[8];
#pragma unroll
    for (int i = 0; i < 8; ++i)
        buf[i] = cp4[i * ABLK + tid];

    // ---- 2. stage targets into LDS ----
    if (tid < T_CNT) {
        float4 bt = reinterpret_cast<const float4*>(bbox_tgts)[b * T_CNT + tid];
        // tlbr -> cthw -> tlbr (reference roundtrip)
        float cx = (bt.x + bt.z) * 0.5f;
        float cy = (bt.y + bt.w) * 0.5f;
        float sx = bt.z - bt.x;
        float sy = bt.w - bt.y;
        float4 tb;
        tb.x = cx - sx * 0.5f;
        tb.y = cy - sy * 0.5f;
        tb.z = cx + sx * 0.5f;
        tb.w = cy + sy * 0.5f;
        tbox[tid] = tb;
        taT[tid]  = sx * sy + 1e-8f;
        tcl[tid]  = clas_tgts[b * T_CNT + tid];
    }
    __syncthreads();

    // ---- 3. match (VALU; prefetches land underneath) ----
    const int a = a0 + tid;
    float4 anc = reinterpret_cast<const float4*>(anchors)[a];
    const float ax1 = anc.x - anc.z * 0.5f;
    const float ay1 = anc.y - anc.w * 0.5f;
    const float ax2 = anc.x + anc.z * 0.5f;
    const float ay2 = anc.y + anc.w * 0.5f;
    const float areaA = anc.z * anc.w;

    float bn = -1.0f, bd = 1.0f;
    int   bj = 0;
#pragma unroll 8
    for (int j = 0; j < T_CNT; ++j) {
        float4 tb = tbox[j];                 // wave-uniform b128 broadcast
        float ix1 = fmaxf(ax1, tb.x);
        float iy1 = fmaxf(ay1, tb.y);
        float ix2 = fminf(ax2, tb.z);
        float iy2 = fminf(ay2, tb.w);
        float w = fmaxf(ix2 - ix1, 0.0f);
        float h = fmaxf(iy2 - iy1, 0.0f);
        float inter = w * h;
        float den = (areaA + taT[j]) - inter;
        if (inter * bd > bn * den) { bn = inter; bd = den; bj = j; }  // first-max
    }

    int   code;
    float bb   = 0.0f;
    float flc  = 0.0f;
    float mloc = 0.0f;

    if (bn > 0.5f * bd) {                    // iou > MATCH_THR
        mloc = 1.0f;
        code = tcl[bj] - 1;                  // hot class in [0,79]
        float4 tb = tbox[bj];
        float gx = (tb.x + tb.z) * 0.5f;
        float gy = (tb.y + tb.w) * 0.5f;
        float gw = tb.z - tb.x;
        float gh = tb.w - tb.y;
        float4 bp = reinterpret_cast<const float4*>(bbox_preds)[(size_t)b * A_CNT + a];
        float t0 = ((gx - anc.x) / anc.z) * 10.0f;       // / SCALE 0.1
        float t1 = ((gy - anc.y) / anc.w) * 10.0f;
        float t2 = __logf(gw / anc.z + 1e-8f) * 5.0f;    // / SCALE 0.2
        float t3 = __logf(gh / anc.w + 1e-8f) * 5.0f;
        float d, ad;
        d = bp.x - t0; ad = fabsf(d); bb += (ad < 1.0f) ? 0.5f * d * d : ad - 0.5f;
        d = bp.y - t1; ad = fabsf(d); bb += (ad < 1.0f) ? 0.5f * d * d : ad - 0.5f;
        d = bp.z - t2; ad = fabsf(d); bb += (ad < 1.0f) ? 0.5f * d * d : ad - 0.5f;
        d = bp.w - t3; ad = fabsf(d); bb += (ad < 1.0f) ? 0.5f * d * d : ad - 0.5f;

        // hot focal correction (L2-warm scattered read; rare threads only)
        float x  = clas_preds[((size_t)b * A_CNT + a) * C_CNT + code];
        float e  = __builtin_amdgcn_exp2f(x * RLN2);
        float t  = 1.0f + e;
        float inv = __builtin_amdgcn_rcpf(t);
        float ps = e * inv;
        float q  = 1.0f - ps;
        float L  = __builtin_amdgcn_logf(t);
        float sp = LN2 * L;                              // softplus(x)
        flc = 0.75f * q * q * (sp - x) - 0.25f * ps * ps * sp;
    } else {
        code = (bn >= 0.4f * bd) ? -2 : -1;  // -2 excluded, -1 background
    }
    codes[tid] = code;
    __syncthreads();

    // ---- 4. hoist per-anchor mask into a 20-bit register mask ----
    unsigned mbits = 0;
#pragma unroll
    for (int k = 0; k < 20; ++k) {
        int al = (unsigned)(k * ABLK + tid) / 20u;
        mbits |= (codes[al] >= -1 ? 1u : 0u) << k;
    }

    // ---- 5. masked focal stream (8-deep reload; minimal loop body) ----
    float acc = 0.0f;
#pragma unroll
    for (int k = 0; k < 12; ++k) {
        f32x4 cur = buf[k & 7];
        buf[k & 7] = cp4[(k + 8) * ABLK + tid];
        float m = (float)((mbits >> k) & 1u);
        acc = fmaf(m, focal4q(cur), acc);
    }
#pragma unroll
    for (int k = 12; k < 20; ++k) {
        float m = (float)((mbits >> k) & 1u);
        acc = fmaf(m, focal4q(buf[k & 7]), acc);
    }
    float fl = fmaf(acc, 0.25f * LN2, flc);   // stream + hot correction

    // ---- 6. block reduction of {bb, fl, m} ----
#pragma unroll
    for (int off = 32; off > 0; off >>= 1) {
        bb   += __shfl_down(bb, off);
        fl   += __shfl_down(fl, off);
        mloc += __shfl_down(mloc, off);
    }
    if (lane == 0) { rv[wave][0] = bb; rv[wave][1] = fl; rv[wave][2] = mloc; }
    __syncthreads();
    if (tid == 0) {
        int slot = b * NBLK + bx;
        bb_part[slot] = rv[0][0] + rv[1][0] + rv[2][0] + rv[3][0];
        fl_part[slot] = rv[0][1] + rv[1][1] + rv[2][1] + rv[3][1];
        m_part[slot]  = rv[0][2] + rv[1][2] + rv[2][2] + rv[3][2];
    }
}

// ---------- Finalize (separate dispatch; coalesced -> LDS -> reduce) ----------
__global__ __launch_bounds__(256) void rnfl_final(
    const float* __restrict__ bb_part,
    const float* __restrict__ fl_part,
    const float* __restrict__ m_part,
    float* __restrict__ out)
{
    __shared__ float bbL[NSLOT], flL[NSLOT], mL[NSLOT];  // 36 KB
    __shared__ float wacc[4];
    const int tid = threadIdx.x, lane = tid & 63, wave = tid >> 6;

#pragma unroll
    for (int k = 0; k < NSLOT / 256; ++k) {   // 12 coalesced loads per array
        int s = k * 256 + tid;
        bbL[s] = bb_part[s];
        flL[s] = fl_part[s];
        mL[s]  = m_part[s];
    }
    __syncthreads();

    float lacc = 0.0f;
    for (int img = wave; img < B_CNT; img += 4) {
        float bb = 0.0f, fl = 0.0f, m = 0.0f;
#pragma unroll
        for (int s = 0; s < 3; ++s) {         // 3*64 = 192 = NBLK
            int i = img * NBLK + s * 64 + lane;
            bb += bbL[i];
            fl += flL[i];
            m  += mL[i];
        }
#pragma unroll
        for (int off = 32; off > 0; off >>= 1) {
            bb += __shfl_down(bb, off);
            fl += __shfl_down(fl, off);
            m  += __shfl_down(m, off);
        }
        if (lane == 0)
            lacc += bb / fmaxf(m * 4.0f, 1.0f) + fl / fmaxf(m, 1.0f);
    }
    if (lane == 0) wacc[wave] = lacc;
    __syncthreads();
    if (tid == 0)
        out[0] = (wacc[0] + wacc[1] + wacc[2] + wacc[3]) / (float)B_CNT;
}

extern "C" void kernel_launch(void* const* d_in, const int* in_sizes, int n_in,
                              void* d_out, int out_size, void* d_ws, size_t ws_size,
                              hipStream_t stream)
{
    const float* clas_preds = (const float*)d_in[0];
    const float* bbox_preds = (const float*)d_in[1];
    const float* bbox_tgts  = (const float*)d_in[2];
    const int*   clas_tgts  = (const int*)d_in[3];
    const float* anchors    = (const float*)d_in[4];
    float* out = (float*)d_out;

    float* bb_part = (float*)d_ws;
    float* fl_part = bb_part + NSLOT;
    float* m_part  = fl_part + NSLOT;

    rnfl_main<<<NSLOT, ABLK, 0, stream>>>(clas_preds, bbox_preds, bbox_tgts,
                                          clas_tgts, anchors,
                                          bb_part, fl_part, m_part);
    rnfl_final<<<1, 256, 0, stream>>>(bb_part, fl_part, m_part, out);
}

// Round 17
// 56.694 us; speedup vs baseline: 1.1929x; 1.0735x over previous
//
#include <hip/hip_runtime.h>

// RetinaNetFocalLoss on MI355X (gfx950).
// Inputs: clas_preds (16,49152,80) f32, bbox_preds (16,49152,4) f32,
//         bbox_tgts (16,64,4) f32 tlbr, clas_tgts (16,64) i32, anchors (49152,4) f32 cthw.
// Output: single f32 scalar.
//
// v17 = v14 VERBATIM (best: 57.2 µs). Fused prefetch-first blocks: each block
// issues its 8-deep focal prefetch FIRST (memory busy from cycle 0), runs
// match while loads fly, then streams focal with a hoisted 20-bit register
// mask. Plain scalar focal4q — both hand-shaped variants (R15 LDS-in-loop,
// R16 pk-packing) regressed; compiler scheduling of this form is optimal.
// Ceiling: ~91% of measured VALU/trans-issue bound (52 µs, R8 counters) and
// 4.6 TB/s logical memory throughput — balanced within ~10%.

#define A_CNT 49152
#define T_CNT 64
#define C_CNT 80
#define ABLK  256
#define NBLK  (A_CNT / ABLK)   // 192
#define B_CNT 16
#define NSLOT (B_CNT * NBLK)   // 3072

#define LN2   0.6931471806f
#define RLN2  1.44269504f

typedef float f32x4 __attribute__((ext_vector_type(4)));

// sum_i sigma(x_i)^2 * log2(1+e^{x_i}) over a float4 (quad-rcp: 4 exp + 1 rcp
// + 4 log). Caller applies mask and the final 0.25*ln2 scale.
__device__ __forceinline__ float focal4q(f32x4 v) {
    float e0 = __builtin_amdgcn_exp2f(v.x * RLN2);
    float e1 = __builtin_amdgcn_exp2f(v.y * RLN2);
    float e2 = __builtin_amdgcn_exp2f(v.z * RLN2);
    float e3 = __builtin_amdgcn_exp2f(v.w * RLN2);
    float t0 = 1.0f + e0, t1 = 1.0f + e1, t2 = 1.0f + e2, t3 = 1.0f + e3;
    float t01 = t0 * t1, t23 = t2 * t3;
    float r   = __builtin_amdgcn_rcpf(t01 * t23);   // 1/(t0 t1 t2 t3)
    float r01 = r * t23, r23 = r * t01;
    float s0 = e0 * (r01 * t1);                     // e_i/t_i
    float s1 = e1 * (r01 * t0);
    float s2 = e2 * (r23 * t3);
    float s3 = e3 * (r23 * t2);
    float L0 = __builtin_amdgcn_logf(t0);
    float L1 = __builtin_amdgcn_logf(t1);
    float L2 = __builtin_amdgcn_logf(t2);
    float L3 = __builtin_amdgcn_logf(t3);
    return ((s0 * s0) * L0 + (s1 * s1) * L1)
         + ((s2 * s2) * L2 + (s3 * s3) * L3);
}

__global__ __launch_bounds__(ABLK) void rnfl_main(
    const float* __restrict__ clas_preds,
    const float* __restrict__ bbox_preds,
    const float* __restrict__ bbox_tgts,
    const int*   __restrict__ clas_tgts,
    const float* __restrict__ anchors,
    float* __restrict__ bb_part,
    float* __restrict__ fl_part,
    float* __restrict__ m_part)
{
    const int tid  = threadIdx.x;
    const int g    = blockIdx.x;                // [0, 3072)
    const int lane = tid & 63, wave = tid >> 6;
    const int b    = g / NBLK;
    const int bx   = g - b * NBLK;
    const int a0   = bx * ABLK;

    __shared__ float4 tbox[T_CNT];
    __shared__ float  taT[T_CNT];
    __shared__ int    tcl[T_CNT];
    __shared__ int    codes[ABLK];
    __shared__ float  rv[4][4];

    const f32x4* cp4 = reinterpret_cast<const f32x4*>(clas_preds)
                     + ((size_t)b * A_CNT + a0) * (C_CNT / 4);

    // ---- 1. issue the focal prefetches FIRST (8 in flight during match) ----
    f32x4 buf[8];
#pragma unroll
    for (int i = 0; i < 8; ++i)
        buf[i] = cp4[i * ABLK + tid];

    // ---- 2. stage targets into LDS ----
    if (tid < T_CNT) {
        float4 bt = reinterpret_cast<const float4*>(bbox_tgts)[b * T_CNT + tid];
        // tlbr -> cthw -> tlbr (reference roundtrip)
        float cx = (bt.x + bt.z) * 0.5f;
        float cy = (bt.y + bt.w) * 0.5f;
        float sx = bt.z - bt.x;
        float sy = bt.w - bt.y;
        float4 tb;
        tb.x = cx - sx * 0.5f;
        tb.y = cy - sy * 0.5f;
        tb.z = cx + sx * 0.5f;
        tb.w = cy + sy * 0.5f;
        tbox[tid] = tb;
        taT[tid]  = sx * sy + 1e-8f;
        tcl[tid]  = clas_tgts[b * T_CNT + tid];
    }
    __syncthreads();

    // ---- 3. match (VALU; prefetches land underneath) ----
    const int a = a0 + tid;
    float4 anc = reinterpret_cast<const float4*>(anchors)[a];
    const float ax1 = anc.x - anc.z * 0.5f;
    const float ay1 = anc.y - anc.w * 0.5f;
    const float ax2 = anc.x + anc.z * 0.5f;
    const float ay2 = anc.y + anc.w * 0.5f;
    const float areaA = anc.z * anc.w;

    float bn = -1.0f, bd = 1.0f;
    int   bj = 0;
#pragma unroll 8
    for (int j = 0; j < T_CNT; ++j) {
        float4 tb = tbox[j];                 // wave-uniform b128 broadcast
        float ix1 = fmaxf(ax1, tb.x);
        float iy1 = fmaxf(ay1, tb.y);
        float ix2 = fminf(ax2, tb.z);
        float iy2 = fminf(ay2, tb.w);
        float w = fmaxf(ix2 - ix1, 0.0f);
        float h = fmaxf(iy2 - iy1, 0.0f);
        float inter = w * h;
        float den = (areaA + taT[j]) - inter;
        if (inter * bd > bn * den) { bn = inter; bd = den; bj = j; }  // first-max
    }

    int   code;
    float bb   = 0.0f;
    float flc  = 0.0f;
    float mloc = 0.0f;

    if (bn > 0.5f * bd) {                    // iou > MATCH_THR
        mloc = 1.0f;
        code = tcl[bj] - 1;                  // hot class in [0,79]
        float4 tb = tbox[bj];
        float gx = (tb.x + tb.z) * 0.5f;
        float gy = (tb.y + tb.w) * 0.5f;
        float gw = tb.z - tb.x;
        float gh = tb.w - tb.y;
        float4 bp = reinterpret_cast<const float4*>(bbox_preds)[(size_t)b * A_CNT + a];
        float t0 = ((gx - anc.x) / anc.z) * 10.0f;       // / SCALE 0.1
        float t1 = ((gy - anc.y) / anc.w) * 10.0f;
        float t2 = __logf(gw / anc.z + 1e-8f) * 5.0f;    // / SCALE 0.2
        float t3 = __logf(gh / anc.w + 1e-8f) * 5.0f;
        float d, ad;
        d = bp.x - t0; ad = fabsf(d); bb += (ad < 1.0f) ? 0.5f * d * d : ad - 0.5f;
        d = bp.y - t1; ad = fabsf(d); bb += (ad < 1.0f) ? 0.5f * d * d : ad - 0.5f;
        d = bp.z - t2; ad = fabsf(d); bb += (ad < 1.0f) ? 0.5f * d * d : ad - 0.5f;
        d = bp.w - t3; ad = fabsf(d); bb += (ad < 1.0f) ? 0.5f * d * d : ad - 0.5f;

        // hot focal correction: stream adds 0.25*ps^2*sp for the hot element;
        // replace with 0.75*(1-ps)^2*softplus(-x). (L2-warm read: the element
        // is inside the slab our prefetches are streaming.)
        float x  = clas_preds[((size_t)b * A_CNT + a) * C_CNT + code];
        float e  = __builtin_amdgcn_exp2f(x * RLN2);
        float t  = 1.0f + e;
        float inv = __builtin_amdgcn_rcpf(t);
        float ps = e * inv;
        float q  = 1.0f - ps;
        float L  = __builtin_amdgcn_logf(t);
        float sp = LN2 * L;                              // softplus(x)
        flc = 0.75f * q * q * (sp - x) - 0.25f * ps * ps * sp;
    } else {
        code = (bn >= 0.4f * bd) ? -2 : -1;  // -2 excluded, -1 background
    }
    codes[tid] = code;
    __syncthreads();

    // ---- 4. hoist per-anchor mask into a 20-bit register mask ----
    unsigned mbits = 0;
#pragma unroll
    for (int k = 0; k < 20; ++k) {
        int al = (unsigned)(k * ABLK + tid) / 20u;
        mbits |= (codes[al] >= -1 ? 1u : 0u) << k;
    }

    // ---- 5. masked focal stream (8-deep reload; minimal loop body) ----
    float acc = 0.0f;
#pragma unroll
    for (int k = 0; k < 12; ++k) {
        f32x4 cur = buf[k & 7];
        buf[k & 7] = cp4[(k + 8) * ABLK + tid];
        float m = (float)((mbits >> k) & 1u);
        acc = fmaf(m, focal4q(cur), acc);
    }
#pragma unroll
    for (int k = 12; k < 20; ++k) {
        float m = (float)((mbits >> k) & 1u);
        acc = fmaf(m, focal4q(buf[k & 7]), acc);
    }
    float fl = fmaf(acc, 0.25f * LN2, flc);   // stream + hot correction

    // ---- 6. block reduction of {bb, fl, m} ----
#pragma unroll
    for (int off = 32; off > 0; off >>= 1) {
        bb   += __shfl_down(bb, off);
        fl   += __shfl_down(fl, off);
        mloc += __shfl_down(mloc, off);
    }
    if (lane == 0) { rv[wave][0] = bb; rv[wave][1] = fl; rv[wave][2] = mloc; }
    __syncthreads();
    if (tid == 0) {
        int slot = b * NBLK + bx;
        bb_part[slot] = rv[0][0] + rv[1][0] + rv[2][0] + rv[3][0];
        fl_part[slot] = rv[0][1] + rv[1][1] + rv[2][1] + rv[3][1];
        m_part[slot]  = rv[0][2] + rv[1][2] + rv[2][2] + rv[3][2];
    }
}

// ---------- Finalize (separate dispatch; coalesced -> LDS -> reduce) ----------
__global__ __launch_bounds__(256) void rnfl_final(
    const float* __restrict__ bb_part,
    const float* __restrict__ fl_part,
    const float* __restrict__ m_part,
    float* __restrict__ out)
{
    __shared__ float bbL[NSLOT], flL[NSLOT], mL[NSLOT];  // 36 KB
    __shared__ float wacc[4];
    const int tid = threadIdx.x, lane = tid & 63, wave = tid >> 6;

#pragma unroll
    for (int k = 0; k < NSLOT / 256; ++k) {   // 12 coalesced loads per array
        int s = k * 256 + tid;
        bbL[s] = bb_part[s];
        flL[s] = fl_part[s];
        mL[s]  = m_part[s];
    }
    __syncthreads();

    float lacc = 0.0f;
    for (int img = wave; img < B_CNT; img += 4) {
        float bb = 0.0f, fl = 0.0f, m = 0.0f;
#pragma unroll
        for (int s = 0; s < 3; ++s) {         // 3*64 = 192 = NBLK
            int i = img * NBLK + s * 64 + lane;
            bb += bbL[i];
            fl += flL[i];
            m  += mL[i];
        }
#pragma unroll
        for (int off = 32; off > 0; off >>= 1) {
            bb += __shfl_down(bb, off);
            fl += __shfl_down(fl, off);
            m  += __shfl_down(m, off);
        }
        if (lane == 0)
            lacc += bb / fmaxf(m * 4.0f, 1.0f) + fl / fmaxf(m, 1.0f);
    }
    if (lane == 0) wacc[wave] = lacc;
    __syncthreads();
    if (tid == 0)
        out[0] = (wacc[0] + wacc[1] + wacc[2] + wacc[3]) / (float)B_CNT;
}

extern "C" void kernel_launch(void* const* d_in, const int* in_sizes, int n_in,
                              void* d_out, int out_size, void* d_ws, size_t ws_size,
                              hipStream_t stream)
{
    const float* clas_preds = (const float*)d_in[0];
    const float* bbox_preds = (const float*)d_in[1];
    const float* bbox_tgts  = (const float*)d_in[2];
    const int*   clas_tgts  = (const int*)d_in[3];
    const float* anchors    = (const float*)d_in[4];
    float* out = (float*)d_out;

    float* bb_part = (float*)d_ws;
    float* fl_part = bb_part + NSLOT;
    float* m_part  = fl_part + NSLOT;

    rnfl_main<<<NSLOT, ABLK, 0, stream>>>(clas_preds, bbox_preds, bbox_tgts,
                                          clas_tgts, anchors,
                                          bb_part, fl_part, m_part);
    rnfl_final<<<1, 256, 0, stream>>>(bb_part, fl_part, m_part, out);
}